// Round 10
// baseline (313.399 us; speedup 1.0000x reference)
//
#include <hip/hip_runtime.h>
#include <hip/hip_bf16.h>

#define NN 100000
#define NE 800000
#define EE 900000   // NE + NN self loops
#define NG 64
#define DH 128
#define DDOC 256
#define DOUT 64
#define BN_EPS 1e-5f
#define SLOPE 0.2f
#define SCAN_CHUNK 2048
#define SCAN_NB ((NN + SCAN_CHUNK - 1) / SCAN_CHUNK)
#define GR 64      // GEMM rows per block
#define BNS_NB 512 // bn_stats blocks
#define SC_RANGES 8
#define SC_RSZ ((NN + SC_RANGES - 1) / SC_RANGES)  // 12500
#define SC_CHUNKS 128

typedef __attribute__((ext_vector_type(8))) short bf16x8;
typedef __attribute__((ext_vector_type(8))) unsigned short u16x8;
typedef __attribute__((ext_vector_type(4))) float f32x4;

__device__ __forceinline__ float lrelu(float x) { return x > 0.f ? x : SLOPE * x; }

// f32 -> bf16 (round to nearest even)
__device__ __forceinline__ ushort f2bf(float f) {
    union { float f; unsigned u; } v; v.f = f;
    unsigned u = v.u;
    unsigned r = (u + 0x7fffu + ((u >> 16) & 1u)) >> 16;
    return (ushort)r;
}
__device__ __forceinline__ float bf2f(ushort u) {
    union { unsigned u; float f; } v; v.u = ((unsigned)u) << 16;
    return v.f;
}

// ---------------- init ----------------
__global__ void k_init(int* counts, int* cursor, float* bn_sums, float* bn_sumsq,
                       float* pool, float* cnt) {
    int i = blockIdx.x * blockDim.x + threadIdx.x;
    if (i < NN) { counts[i] = 1; cursor[i] = 0; }   // 1 = self loop
    if (i < DH) { bn_sums[i] = 0.f; bn_sumsq[i] = 0.f; }
    if (i < NG * DH) pool[i] = 0.f;
    if (i < NG) cnt[i] = 0.f;
}

// ---------------- W pre-pack into per-lane MFMA B-fragment order (bf16) ----------------
__global__ void k_wpack(const float* __restrict__ W1, const float* __restrict__ W2,
                        ushort* __restrict__ P1, ushort* __restrict__ P2) {
    const float* W = blockIdx.x ? W2 : W1;
    ushort* P = blockIdx.x ? P2 : P1;
    for (int idx = threadIdx.x; idx < 16384; idx += 256) {
        int j = idx & 7;
        int lane = (idx >> 3) & 63;
        int kc = idx >> 9;             // 0..31
        int ct = kc & 7, k = kc >> 3;
        int kk = k * 32 + ((lane >> 4) * 8) + j;
        int col = ct * 16 + (lane & 15);
        P[idx] = f2bf(W[kk * 128 + col]);
    }
}

// ---------------- fused MFMA GEMM + attention dots ----------------
// H (bf16) = X @ W ; as_/ad_ from f32 accumulators.
template <bool BF16IN>
__global__ __launch_bounds__(256) void k_gemm_att(
        const void* __restrict__ Xv, const ushort* __restrict__ Wp,
        const float* __restrict__ a_s, const float* __restrict__ a_d,
        ushort* __restrict__ H, float* __restrict__ as_, float* __restrict__ ad_,
        int nrows) {
    __shared__ ushort As[GR * DH];   // 16 KB, XOR-swizzled rows (byte ^= (row&7)<<4)
    int t = threadIdx.x;
    int wv = t >> 6, lane = t & 63;
    int g = lane >> 4, l15 = lane & 15;
    int r0 = blockIdx.x * GR;
    if constexpr (BF16IN) {
        const ushort* X = (const ushort*)Xv;
        #pragma unroll
        for (int i = 0; i < 4; ++i) {
            int row = i * 16 + (t >> 4);
            int col = (t & 15) * 8;
            int gr = r0 + row;
            bf16x8 v = (bf16x8){0, 0, 0, 0, 0, 0, 0, 0};
            if (gr < nrows) v = *(const bf16x8*)(X + (size_t)gr * DH + col);
            int boff = row * 256 + ((col * 2) ^ ((row & 7) << 4));
            *(bf16x8*)((char*)As + boff) = v;
        }
    } else {
        const float* X = (const float*)Xv;
        #pragma unroll
        for (int i = 0; i < 8; ++i) {
            int row = i * 8 + (t >> 5);
            int col = (t & 31) * 4;
            int gr = r0 + row;
            float4 v = (gr < nrows) ? *(const float4*)(X + (size_t)gr * DH + col)
                                    : make_float4(0.f, 0.f, 0.f, 0.f);
            ushort4 pk;
            pk.x = f2bf(v.x); pk.y = f2bf(v.y); pk.z = f2bf(v.z); pk.w = f2bf(v.w);
            int boff = row * 256 + ((col * 2) ^ ((row & 7) << 4));
            *(ushort4*)((char*)As + boff) = pk;
        }
    }
    __syncthreads();

    f32x4 acc[8];
    #pragma unroll
    for (int ct = 0; ct < 8; ++ct) acc[ct] = (f32x4){0.f, 0.f, 0.f, 0.f};
    int arow = wv * 16 + l15;
    int abase = arow * 256;
    int aswz = (arow & 7) << 4;
    #pragma unroll
    for (int k = 0; k < 4; ++k) {
        bf16x8 a = *(const bf16x8*)((const char*)As + abase + ((k * 64 + g * 16) ^ aswz));
        #pragma unroll
        for (int ct = 0; ct < 8; ++ct) {
            bf16x8 b = *(const bf16x8*)(Wp + (((k * 8 + ct) * 64 + lane) << 3));
            acc[ct] = __builtin_amdgcn_mfma_f32_16x16x32_bf16(a, b, acc[ct], 0, 0, 0);
        }
    }

    // epilogue: H store (bf16) + attention dots (row fully wave-local)
    float asv[8], adv[8];
    #pragma unroll
    for (int ct = 0; ct < 8; ++ct) {
        asv[ct] = a_s[ct * 16 + l15];
        adv[ct] = a_d[ct * 16 + l15];
    }
    int rbase = r0 + wv * 16 + g * 4;
    #pragma unroll
    for (int r = 0; r < 4; ++r) {
        int gr = rbase + r;
        bool ok = gr < nrows;
        float ps = 0.f, pd = 0.f;
        #pragma unroll
        for (int ct = 0; ct < 8; ++ct) {
            float v = acc[ct][r];
            ps = fmaf(v, asv[ct], ps);
            pd = fmaf(v, adv[ct], pd);
            if (ok) H[(size_t)gr * DH + ct * 16 + l15] = f2bf(v);
        }
        ps += __shfl_xor(ps, 1); pd += __shfl_xor(pd, 1);
        ps += __shfl_xor(ps, 2); pd += __shfl_xor(pd, 2);
        ps += __shfl_xor(ps, 4); pd += __shfl_xor(pd, 4);
        ps += __shfl_xor(ps, 8); pd += __shfl_xor(pd, 8);
        if (ok && l15 == 0) { as_[gr] = ps; ad_[gr] = pd; }
    }
}

// ---------------- CSR build ----------------
__global__ void k_hist(const int* __restrict__ ei, int* counts) {
    int e = blockIdx.x * blockDim.x + threadIdx.x;
    if (e < NE) atomicAdd(&counts[ei[NE + e]], 1);
}

__global__ void k_scan1(const int* __restrict__ counts, int* __restrict__ row_ptr,
                        int* __restrict__ bsum) {
    __shared__ int sc[256];
    int t = threadIdx.x;
    int base = blockIdx.x * SCAN_CHUNK;
    int v[8];
    int run = 0;
    #pragma unroll
    for (int j = 0; j < 8; ++j) {
        int idx = base + t * 8 + j;
        int x = (idx < NN) ? counts[idx] : 0;
        run += x; v[j] = run;
    }
    sc[t] = run;
    __syncthreads();
    for (int off = 1; off < 256; off <<= 1) {
        int add = (t >= off) ? sc[t - off] : 0;
        __syncthreads();
        sc[t] += add;
        __syncthreads();
    }
    int excl = sc[t] - run;
    #pragma unroll
    for (int j = 0; j < 8; ++j) {
        int idx = base + t * 8 + j;
        if (idx < NN) row_ptr[idx + 1] = excl + v[j];
    }
    if (t == 255) bsum[blockIdx.x] = sc[255];
}

__global__ void k_scan2(int* bsum, int* row_ptr) {
    if (blockIdx.x == 0 && threadIdx.x == 0) {
        int run = 0;
        for (int b = 0; b < SCAN_NB; ++b) { int x = bsum[b]; bsum[b] = run; run += x; }
        row_ptr[0] = 0;
    }
}

__global__ void k_scan3(int* row_ptr, const int* __restrict__ bsum) {
    int base = blockIdx.x * SCAN_CHUNK;
    int add = bsum[blockIdx.x];
    for (int j = threadIdx.x; j < SCAN_CHUNK; j += blockDim.x) {
        int idx = base + j;
        if (idx < NN) row_ptr[idx + 1] += add;
    }
}

// dst-range-partitioned scatter (XCD-local csr_src lines)
__global__ __launch_bounds__(256) void k_scatter(const int* __restrict__ ei,
                          const int* __restrict__ row_ptr,
                          int* cursor, int* __restrict__ csr_src) {
    int rng = blockIdx.x & (SC_RANGES - 1);
    int rlo = rng * SC_RSZ;
    int rhi = min(rlo + SC_RSZ, NN);
    int ch = blockIdx.x >> 3;
    for (int e = ch * 256 + threadIdx.x; e < EE; e += SC_CHUNKS * 256) {
        int d = (e < NE) ? ei[NE + e] : e - NE;
        if (d >= rlo && d < rhi) {
            int s = (e < NE) ? ei[e] : d;
            int slot = row_ptr[d] + atomicAdd(&cursor[d], 1);
            csr_src[slot] = s;
        }
    }
}

// ---------------- GAT aggregation: one wave per node, 8 edges/iter, bf16 rows ----------------
// 4 groups x 2 edges each; lane loads 8 bf16 dims (16 B); depth-2 data prefetch.
__global__ __launch_bounds__(256) void k_gat_agg(
        const ushort* __restrict__ H, const float* __restrict__ as_,
        const float* __restrict__ ad_, const int* __restrict__ row_ptr,
        const int* __restrict__ csr_src, const float* __restrict__ bias,
        ushort* __restrict__ OUT) {
    int wid = (blockIdx.x * blockDim.x + threadIdx.x) >> 6;
    int lane = threadIdx.x & 63;
    if (wid >= NN) return;
    int grp = lane >> 4, l15 = lane & 15;
    int beg = row_ptr[wid], end = row_ptr[wid + 1];
    float adn = ad_[wid];
    float ssum = 0.f;
    float facc[8];
    #pragma unroll
    for (int d = 0; d < 8; ++d) facc[d] = 0.f;

    for (int cb = beg; cb < end; cb += 64) {
        int cn = min(64, end - cb);
        int s = 0;
        float w = 0.f;
        if (lane < cn) {
            s = csr_src[cb + lane];                     // coalesced
            w = __expf(lrelu(as_[s] + adn));            // parallel gather + exp
        }
        // wave-wide softmax denominator (out of the serial loop)
        float ws = w;
        #pragma unroll
        for (int o = 32; o > 0; o >>= 1) ws += __shfl_xor(ws, o);
        ssum += ws;

        int nIter = (cn + 7) >> 3;
        int e0 = grp * 2;
        int s0 = __shfl(s, e0);
        int s1 = __shfl(s, e0 + 1);
        u16x8 h0 = *(const u16x8*)(H + (size_t)s0 * DH + l15 * 8);
        u16x8 h1 = *(const u16x8*)(H + (size_t)s1 * DH + l15 * 8);
        for (int it = 0; it < nIter; ++it) {
            u16x8 n0 = h0, n1 = h1;
            if (it + 1 < nIter) {
                int t0 = __shfl(s, (it + 1) * 8 + e0);
                int t1 = __shfl(s, (it + 1) * 8 + e0 + 1);
                n0 = *(const u16x8*)(H + (size_t)t0 * DH + l15 * 8);
                n1 = *(const u16x8*)(H + (size_t)t1 * DH + l15 * 8);
            }
            float w0 = __shfl(w, it * 8 + e0);
            float w1 = __shfl(w, it * 8 + e0 + 1);
            #pragma unroll
            for (int d = 0; d < 8; ++d)
                facc[d] = fmaf(w0, bf2f(h0[d]), facc[d]);
            #pragma unroll
            for (int d = 0; d < 8; ++d)
                facc[d] = fmaf(w1, bf2f(h1[d]), facc[d]);
            h0 = n0; h1 = n1;
        }
    }
    // cross-group reduce (groups 0..3 hold partials of the same dims)
    #pragma unroll
    for (int d = 0; d < 8; ++d) {
        facc[d] += __shfl_xor(facc[d], 16);
        facc[d] += __shfl_xor(facc[d], 32);
    }
    float inv = 1.0f / ssum;
    if (grp == 0) {
        u16x8 pk;
        #pragma unroll
        for (int d = 0; d < 8; ++d) {
            float o = fmaxf(fmaf(facc[d], inv, bias[l15 * 8 + d]), 0.f);
            pk[d] = f2bf(o);
        }
        *(u16x8*)(OUT + (size_t)wid * DH + l15 * 8) = pk;
    }
}

// ---------------- BatchNorm stats: per-block partials, no global atomics ----------------
__global__ __launch_bounds__(256) void k_bn_stats(const ushort* __restrict__ H,
                                                  float* __restrict__ partial) {
    __shared__ float rs[8][DH], rq[8][DH];   // 8 KB
    int t = threadIdx.x;
    int cg = (t & 31) * 4;   // col group of 4
    int rl = t >> 5;         // row lane 0..7
    float4 s = make_float4(0.f, 0.f, 0.f, 0.f);
    float4 q = make_float4(0.f, 0.f, 0.f, 0.f);
    for (int r = blockIdx.x * 8 + rl; r < NN; r += BNS_NB * 8) {
        ushort4 u = *(const ushort4*)(H + (size_t)r * DH + cg);
        float vx = bf2f(u.x), vy = bf2f(u.y), vz = bf2f(u.z), vw = bf2f(u.w);
        s.x += vx; q.x = fmaf(vx, vx, q.x);
        s.y += vy; q.y = fmaf(vy, vy, q.y);
        s.z += vz; q.z = fmaf(vz, vz, q.z);
        s.w += vw; q.w = fmaf(vw, vw, q.w);
    }
    *(float4*)(&rs[rl][cg]) = s;
    *(float4*)(&rq[rl][cg]) = q;
    __syncthreads();
    int c = t & 127;
    float acc = 0.f;
    if (t < 128) {
        #pragma unroll
        for (int i = 0; i < 8; ++i) acc += rs[i][c];
    } else {
        #pragma unroll
        for (int i = 0; i < 8; ++i) acc += rq[i][c];
    }
    partial[blockIdx.x * 256 + t] = acc;   // coalesced 1KB store per block
}

// reduce partials: 16 blocks x 256 thr
__global__ void k_bn_red(const float* __restrict__ partial,
                         float* bn_sums, float* bn_sumsq) {
    int t = threadIdx.x;
    float acc = 0.f;
    for (int b = blockIdx.x; b < BNS_NB; b += 16)
        acc += partial[b * 256 + t];
    if (t < 128) atomicAdd(&bn_sums[t], acc);
    else         atomicAdd(&bn_sumsq[t - 128], acc);
}

__global__ void k_bn_fin(const float* bn_sums, const float* bn_sumsq,
                         const float* __restrict__ g_, const float* __restrict__ b_,
                         float* scale, float* shift) {
    int c = threadIdx.x;  // 128
    float mu = bn_sums[c] / (float)NN;
    float var = bn_sumsq[c] / (float)NN - mu * mu;
    float sc = g_[c] * rsqrtf(var + BN_EPS);
    scale[c] = sc;
    shift[c] = fmaf(-mu, sc, b_[c]);
}

// fused BN-apply + relu + segment-mean-pool (batch sorted), bf16 H
__global__ __launch_bounds__(256) void k_bn_pool(const ushort* __restrict__ H,
                          const float* __restrict__ scale, const float* __restrict__ shift,
                          const int* __restrict__ batch, float* pool, float* cnt) {
    int t = threadIdx.x;
    int c2 = (t & 63) * 2;
    int rl = t >> 6;       // 0..3, wave-uniform
    int r0 = blockIdx.x * 128;
    if (r0 >= NN) return;
    int rend = min(r0 + 128, NN);
    float sc0 = scale[c2], sh0 = shift[c2];
    float sc1 = scale[c2 + 1], sh1 = shift[c2 + 1];
    float a0 = 0.f, a1 = 0.f, rcnt = 0.f;
    int curg = batch[min(r0 + rl, NN - 1)];
    for (int r = r0 + rl; r < rend; r += 4) {
        int g = batch[r];   // wave-uniform scalar load
        if (g != curg) {
            atomicAdd(&pool[curg * DH + c2], a0);
            atomicAdd(&pool[curg * DH + c2 + 1], a1);
            if ((t & 63) == 0) atomicAdd(&cnt[curg], rcnt);
            a0 = 0.f; a1 = 0.f; rcnt = 0.f; curg = g;
        }
        ushort2 u = *((const ushort2*)(H + (size_t)r * DH) + (t & 63));
        a0 += fmaxf(fmaf(bf2f(u.x), sc0, sh0), 0.f);
        a1 += fmaxf(fmaf(bf2f(u.y), sc1, sh1), 0.f);
        rcnt += 1.f;
    }
    atomicAdd(&pool[curg * DH + c2], a0);
    atomicAdd(&pool[curg * DH + c2 + 1], a1);
    if ((t & 63) == 0) atomicAdd(&cnt[curg], rcnt);
}

// ---------------- head (ILP-restructured) ----------------
__global__ __launch_bounds__(256) void k_head_docf(
        const float* __restrict__ docf, const float* __restrict__ doc_W,
        const float* __restrict__ doc_b, const float* __restrict__ pool,
        const float* __restrict__ cnt, float* __restrict__ f) {
    __shared__ float4 red[8][32];   // 4 KB
    int g = blockIdx.x;   // 64
    int t = threadIdx.x;  // 256
    int cq = t & 31, kq = t >> 5;
    const float* dr = docf + g * DDOC;
    float4 acc = make_float4(0.f, 0.f, 0.f, 0.f);
    #pragma unroll 8
    for (int i = 0; i < 32; ++i) {
        int k = kq + i * 8;
        float dv = dr[k];
        float4 w = *(const float4*)(doc_W + k * DH + cq * 4);
        acc.x = fmaf(dv, w.x, acc.x);
        acc.y = fmaf(dv, w.y, acc.y);
        acc.z = fmaf(dv, w.z, acc.z);
        acc.w = fmaf(dv, w.w, acc.w);
    }
    red[kq][cq] = acc;
    __syncthreads();
    if (t < 32) {
        float4 s = red[0][t];
        #pragma unroll
        for (int i = 1; i < 8; ++i) {
            float4 a = red[i][t];
            s.x += a.x; s.y += a.y; s.z += a.z; s.w += a.w;
        }
        float4 b4 = *(const float4*)(doc_b + t * 4);
        s.x = fmaxf(s.x + b4.x, 0.f);
        s.y = fmaxf(s.y + b4.y, 0.f);
        s.z = fmaxf(s.z + b4.z, 0.f);
        s.w = fmaxf(s.w + b4.w, 0.f);
        *(float4*)(f + g * 2 * DH + DH + t * 4) = s;
    } else if (t >= 128) {
        int c = t - 128;
        f[g * 2 * DH + c] = pool[g * DH + c] / fmaxf(cnt[g], 1.0f);
    }
}

__global__ void k_head_bnf(const float* __restrict__ f, const float* __restrict__ g_,
                           const float* __restrict__ b_, float* __restrict__ fn) {
    int c = threadIdx.x;  // 256
    float s = 0.f, q = 0.f;
    #pragma unroll 16
    for (int r = 0; r < NG; ++r) {
        float v = f[r * 2 * DH + c];
        s += v; q = fmaf(v, v, q);
    }
    float mu = s / (float)NG;
    float var = q / (float)NG - mu * mu;
    float sc = g_[c] * rsqrtf(var + BN_EPS);
    float sh = fmaf(-mu, sc, b_[c]);
    #pragma unroll 16
    for (int r = 0; r < NG; ++r)
        fn[r * 2 * DH + c] = fmaf(f[r * 2 * DH + c], sc, sh);
}

__global__ __launch_bounds__(256) void k_head_out(
        const float* __restrict__ fn, const float* __restrict__ fus_W,
        const float* __restrict__ fus_b, const float* __restrict__ task_W,
        const float* __restrict__ task_b, const float* __restrict__ time_W,
        const float* __restrict__ time_b, float* __restrict__ out) {
    __shared__ float4 red[8][32];   // 4 KB (reused by stage 2 as [16][16])
    __shared__ float ff[DH];
    int g = blockIdx.x;   // 64
    int t = threadIdx.x;  // 256
    const float* fr = fn + g * 2 * DH;
    {
        int cq = t & 31, kq = t >> 5;
        float4 acc = make_float4(0.f, 0.f, 0.f, 0.f);
        #pragma unroll 8
        for (int i = 0; i < 32; ++i) {
            int k = kq + i * 8;
            float fv = fr[k];
            float4 w = *(const float4*)(fus_W + k * DH + cq * 4);
            acc.x = fmaf(fv, w.x, acc.x);
            acc.y = fmaf(fv, w.y, acc.y);
            acc.z = fmaf(fv, w.z, acc.z);
            acc.w = fmaf(fv, w.w, acc.w);
        }
        red[kq][cq] = acc;
    }
    __syncthreads();
    if (t < 32) {
        float4 s = red[0][t];
        #pragma unroll
        for (int i = 1; i < 8; ++i) {
            float4 a = red[i][t];
            s.x += a.x; s.y += a.y; s.z += a.z; s.w += a.w;
        }
        float4 b4 = *(const float4*)(fus_b + t * 4);
        ff[t * 4 + 0] = fmaxf(s.x + b4.x, 0.f);
        ff[t * 4 + 1] = fmaxf(s.y + b4.y, 0.f);
        ff[t * 4 + 2] = fmaxf(s.z + b4.z, 0.f);
        ff[t * 4 + 3] = fmaxf(s.w + b4.w, 0.f);
    }
    __syncthreads();
    {
        int cq = t & 15, kq = t >> 4;
        float4 acc = make_float4(0.f, 0.f, 0.f, 0.f);
        #pragma unroll
        for (int i = 0; i < 8; ++i) {
            int k = kq + i * 16;
            float fv = ff[k];
            float4 w = *(const float4*)(task_W + k * DOUT + cq * 4);
            acc.x = fmaf(fv, w.x, acc.x);
            acc.y = fmaf(fv, w.y, acc.y);
            acc.z = fmaf(fv, w.z, acc.z);
            acc.w = fmaf(fv, w.w, acc.w);
        }
        float4* red2 = (float4*)red;
        red2[kq * 16 + cq] = acc;
    }
    float tp = 0.f;
    if (t >= 64 && t < 128) {
        int k = t - 64;
        tp = fmaf(ff[k], time_W[k], ff[k + 64] * time_W[k + 64]);
    }
    __syncthreads();
    if (t < 16) {
        const float4* red2 = (const float4*)red;
        float4 s = red2[t];
        #pragma unroll
        for (int i = 1; i < 16; ++i) {
            float4 a = red2[i * 16 + t];
            s.x += a.x; s.y += a.y; s.z += a.z; s.w += a.w;
        }
        float4 b4 = *(const float4*)(task_b + t * 4);
        s.x += b4.x; s.y += b4.y; s.z += b4.z; s.w += b4.w;
        *(float4*)(out + g * DOUT + t * 4) = s;
    }
    if (t >= 64 && t < 128) {
        #pragma unroll
        for (int o = 32; o > 0; o >>= 1) tp += __shfl_xor(tp, o);
        if (t == 64) out[NG * DOUT + g] = tp + time_b[0];
    }
}

extern "C" void kernel_launch(void* const* d_in, const int* in_sizes, int n_in,
                              void* d_out, int out_size, void* d_ws, size_t ws_size,
                              hipStream_t stream) {
    const float* x      = (const float*)d_in[0];
    const int*   ei     = (const int*)d_in[1];
    const int*   batch  = (const int*)d_in[2];
    const float* docf   = (const float*)d_in[3];
    const float* W1     = (const float*)d_in[4];
    const float* a_src1 = (const float*)d_in[5];
    const float* a_dst1 = (const float*)d_in[6];
    const float* b1     = (const float*)d_in[7];
    const float* W2     = (const float*)d_in[8];
    const float* a_src2 = (const float*)d_in[9];
    const float* a_dst2 = (const float*)d_in[10];
    const float* b2     = (const float*)d_in[11];
    const float* bn2_g  = (const float*)d_in[12];
    const float* bn2_b  = (const float*)d_in[13];
    const float* doc_W  = (const float*)d_in[14];
    const float* doc_b  = (const float*)d_in[15];
    const float* bnf_g  = (const float*)d_in[16];
    const float* bnf_b  = (const float*)d_in[17];
    const float* fus_W  = (const float*)d_in[18];
    const float* fus_b  = (const float*)d_in[19];
    const float* task_W = (const float*)d_in[20];
    const float* task_b = (const float*)d_in[21];
    const float* time_W = (const float*)d_in[22];
    const float* time_b = (const float*)d_in[23];
    float* out = (float*)d_out;

    char* p = (char*)d_ws;
    size_t off = 0;
    auto alloc = [&](size_t bytes) {
        void* r = p + off;
        off += (bytes + 255) & ~(size_t)255;
        return r;
    };
    ushort* hA     = (ushort*)alloc((size_t)NN * DH * 2);  // GEMM out (bf16)
    ushort* hB     = (ushort*)alloc((size_t)NN * DH * 2);  // agg out (bf16)
    float* as_     = (float*)alloc(NN * 4);
    float* ad_     = (float*)alloc(NN * 4);
    int*   row_ptr = (int*)  alloc((NN + 1) * 4);
    int*   counts  = (int*)  alloc(NN * 4);
    int*   cursor  = (int*)  alloc(NN * 4);
    int*   csr_src = (int*)  alloc((size_t)EE * 4);
    int*   bsum    = (int*)  alloc(SCAN_NB * 4);
    float* bn_sums = (float*)alloc(DH * 4);
    float* bn_sumsq= (float*)alloc(DH * 4);
    float* scale   = (float*)alloc(DH * 4);
    float* shift   = (float*)alloc(DH * 4);
    float* pool    = (float*)alloc(NG * DH * 4);
    float* cnt     = (float*)alloc(NG * 4);
    float* f       = (float*)alloc(NG * 2 * DH * 4);
    float* fnrm    = (float*)alloc(NG * 2 * DH * 4);
    ushort* Wp1    = (ushort*)alloc(16384 * 2);
    ushort* Wp2    = (ushort*)alloc(16384 * 2);
    float* bn_part = (float*)alloc((size_t)BNS_NB * 256 * 4);  // 512 KB
    (void)ws_size; (void)in_sizes; (void)n_in; (void)out_size;

    auto cdiv = [](int a, int b) { return (a + b - 1) / b; };

    k_init<<<cdiv(NN, 256), 256, 0, stream>>>(counts, cursor, bn_sums, bn_sumsq, pool, cnt);
    k_wpack<<<2, 256, 0, stream>>>(W1, W2, Wp1, Wp2);

    // CSR build (shared by both layers)
    k_hist<<<cdiv(NE, 256), 256, 0, stream>>>(ei, counts);
    k_scan1<<<SCAN_NB, 256, 0, stream>>>(counts, row_ptr, bsum);
    k_scan2<<<1, 64, 0, stream>>>(bsum, row_ptr);
    k_scan3<<<SCAN_NB, 256, 0, stream>>>(row_ptr, bsum);
    k_scatter<<<SC_RANGES * SC_CHUNKS, 256, 0, stream>>>(ei, row_ptr, cursor, csr_src);

    // GAT layer 1
    k_gemm_att<false><<<cdiv(NN, GR), 256, 0, stream>>>(x, Wp1, a_src1, a_dst1, hA, as_, ad_, NN);
    k_gat_agg<<<cdiv(NN, 4), 256, 0, stream>>>(hA, as_, ad_, row_ptr, csr_src, b1, hB);

    // GAT layer 2 (input hB is bf16)
    k_gemm_att<true><<<cdiv(NN, GR), 256, 0, stream>>>(hB, Wp2, a_src2, a_dst2, hA, as_, ad_, NN);
    k_gat_agg<<<cdiv(NN, 4), 256, 0, stream>>>(hA, as_, ad_, row_ptr, csr_src, b2, hB);

    // BN + relu + mean-pool
    k_bn_stats<<<BNS_NB, 256, 0, stream>>>(hB, bn_part);
    k_bn_red<<<16, 256, 0, stream>>>(bn_part, bn_sums, bn_sumsq);
    k_bn_fin<<<1, 128, 0, stream>>>(bn_sums, bn_sumsq, bn2_g, bn2_b, scale, shift);
    k_bn_pool<<<cdiv(NN, 128), 256, 0, stream>>>(hB, scale, shift, batch, pool, cnt);

    // head
    k_head_docf<<<NG, 256, 0, stream>>>(docf, doc_W, doc_b, pool, cnt, f);
    k_head_bnf<<<1, 256, 0, stream>>>(f, bnf_g, bnf_b, fnrm);
    k_head_out<<<NG, 256, 0, stream>>>(fnrm, fus_W, fus_b, task_W, task_b, time_W, time_b, out);
}

// Round 11
// 307.502 us; speedup vs baseline: 1.0192x; 1.0192x over previous
//
#include <hip/hip_runtime.h>
#include <hip/hip_bf16.h>

#define NN 100000
#define NE 800000
#define EE 900000   // NE + NN self loops
#define NG 64
#define DH 128
#define DDOC 256
#define DOUT 64
#define BN_EPS 1e-5f
#define SLOPE 0.2f
#define SCAN_CHUNK 2048
#define SCAN_NB ((NN + SCAN_CHUNK - 1) / SCAN_CHUNK)
#define GR 64      // GEMM rows per block
#define BNS_NB 512 // bn_stats blocks
#define SC_RANGES 8
#define SC_RSZ ((NN + SC_RANGES - 1) / SC_RANGES)  // 12500
#define SC_CHUNKS 128

typedef __attribute__((ext_vector_type(8))) short bf16x8;
typedef __attribute__((ext_vector_type(8))) unsigned short u16x8;
typedef __attribute__((ext_vector_type(4))) float f32x4;

__device__ __forceinline__ float lrelu(float x) { return x > 0.f ? x : SLOPE * x; }

// f32 -> bf16 (round to nearest even)
__device__ __forceinline__ ushort f2bf(float f) {
    union { float f; unsigned u; } v; v.f = f;
    unsigned u = v.u;
    unsigned r = (u + 0x7fffu + ((u >> 16) & 1u)) >> 16;
    return (ushort)r;
}
__device__ __forceinline__ float bf2f(ushort u) {
    union { unsigned u; float f; } v; v.u = ((unsigned)u) << 16;
    return v.f;
}

// ---------------- merged W pre-pack (blocks 0-1) + edge histogram (blocks 2+) ----------------
// Wp[((k*8 + ct)*64 + lane)*8 + j] = W[k*32 + (lane>>4)*8 + j][ct*16 + (lane&15)]
__global__ void k_wpack_hist(const float* __restrict__ W1, const float* __restrict__ W2,
                             ushort* __restrict__ P1, ushort* __restrict__ P2,
                             const int* __restrict__ ei, int* counts) {
    if (blockIdx.x < 2) {
        const float* W = blockIdx.x ? W2 : W1;
        ushort* P = blockIdx.x ? P2 : P1;
        for (int idx = threadIdx.x; idx < 16384; idx += 256) {
            int j = idx & 7;
            int lane = (idx >> 3) & 63;
            int kc = idx >> 9;             // 0..31
            int ct = kc & 7, k = kc >> 3;
            int kk = k * 32 + ((lane >> 4) * 8) + j;
            int col = ct * 16 + (lane & 15);
            P[idx] = f2bf(W[kk * 128 + col]);
        }
    } else {
        int e = (blockIdx.x - 2) * 256 + threadIdx.x;
        if (e < NE) atomicAdd(&counts[ei[NE + e]], 1);
    }
}

// ---------------- fused MFMA GEMM + attention dots ----------------
// H (bf16) = X @ W ; as_/ad_ from f32 accumulators.
template <bool BF16IN>
__global__ __launch_bounds__(256) void k_gemm_att(
        const void* __restrict__ Xv, const ushort* __restrict__ Wp,
        const float* __restrict__ a_s, const float* __restrict__ a_d,
        ushort* __restrict__ H, float* __restrict__ as_, float* __restrict__ ad_,
        int nrows) {
    __shared__ ushort As[GR * DH];   // 16 KB, XOR-swizzled rows (byte ^= (row&7)<<4)
    int t = threadIdx.x;
    int wv = t >> 6, lane = t & 63;
    int g = lane >> 4, l15 = lane & 15;
    int r0 = blockIdx.x * GR;
    if constexpr (BF16IN) {
        const ushort* X = (const ushort*)Xv;
        #pragma unroll
        for (int i = 0; i < 4; ++i) {
            int row = i * 16 + (t >> 4);
            int col = (t & 15) * 8;
            int gr = r0 + row;
            bf16x8 v = (bf16x8){0, 0, 0, 0, 0, 0, 0, 0};
            if (gr < nrows) v = *(const bf16x8*)(X + (size_t)gr * DH + col);
            int boff = row * 256 + ((col * 2) ^ ((row & 7) << 4));
            *(bf16x8*)((char*)As + boff) = v;
        }
    } else {
        const float* X = (const float*)Xv;
        #pragma unroll
        for (int i = 0; i < 8; ++i) {
            int row = i * 8 + (t >> 5);
            int col = (t & 31) * 4;
            int gr = r0 + row;
            float4 v = (gr < nrows) ? *(const float4*)(X + (size_t)gr * DH + col)
                                    : make_float4(0.f, 0.f, 0.f, 0.f);
            ushort4 pk;
            pk.x = f2bf(v.x); pk.y = f2bf(v.y); pk.z = f2bf(v.z); pk.w = f2bf(v.w);
            int boff = row * 256 + ((col * 2) ^ ((row & 7) << 4));
            *(ushort4*)((char*)As + boff) = pk;
        }
    }
    __syncthreads();

    f32x4 acc[8];
    #pragma unroll
    for (int ct = 0; ct < 8; ++ct) acc[ct] = (f32x4){0.f, 0.f, 0.f, 0.f};
    int arow = wv * 16 + l15;
    int abase = arow * 256;
    int aswz = (arow & 7) << 4;
    #pragma unroll
    for (int k = 0; k < 4; ++k) {
        bf16x8 a = *(const bf16x8*)((const char*)As + abase + ((k * 64 + g * 16) ^ aswz));
        #pragma unroll
        for (int ct = 0; ct < 8; ++ct) {
            bf16x8 b = *(const bf16x8*)(Wp + (((k * 8 + ct) * 64 + lane) << 3));
            acc[ct] = __builtin_amdgcn_mfma_f32_16x16x32_bf16(a, b, acc[ct], 0, 0, 0);
        }
    }

    // epilogue: H store (bf16) + attention dots (row fully wave-local)
    float asv[8], adv[8];
    #pragma unroll
    for (int ct = 0; ct < 8; ++ct) {
        asv[ct] = a_s[ct * 16 + l15];
        adv[ct] = a_d[ct * 16 + l15];
    }
    int rbase = r0 + wv * 16 + g * 4;
    #pragma unroll
    for (int r = 0; r < 4; ++r) {
        int gr = rbase + r;
        bool ok = gr < nrows;
        float ps = 0.f, pd = 0.f;
        #pragma unroll
        for (int ct = 0; ct < 8; ++ct) {
            float v = acc[ct][r];
            ps = fmaf(v, asv[ct], ps);
            pd = fmaf(v, adv[ct], pd);
            if (ok) H[(size_t)gr * DH + ct * 16 + l15] = f2bf(v);
        }
        ps += __shfl_xor(ps, 1); pd += __shfl_xor(pd, 1);
        ps += __shfl_xor(ps, 2); pd += __shfl_xor(pd, 2);
        ps += __shfl_xor(ps, 4); pd += __shfl_xor(pd, 4);
        ps += __shfl_xor(ps, 8); pd += __shfl_xor(pd, 8);
        if (ok && l15 == 0) { as_[gr] = ps; ad_[gr] = pd; }
    }
}

// ---------------- CSR build ----------------
// scan1: prefix of (counts[i] + 1) — the +1 folds in the self loop (counts start at 0)
__global__ void k_scan1(const int* __restrict__ counts, int* __restrict__ row_ptr,
                        int* __restrict__ bsum) {
    __shared__ int sc[256];
    int t = threadIdx.x;
    int base = blockIdx.x * SCAN_CHUNK;
    int v[8];
    int run = 0;
    #pragma unroll
    for (int j = 0; j < 8; ++j) {
        int idx = base + t * 8 + j;
        int x = (idx < NN) ? counts[idx] + 1 : 0;
        run += x; v[j] = run;
    }
    sc[t] = run;
    __syncthreads();
    for (int off = 1; off < 256; off <<= 1) {
        int add = (t >= off) ? sc[t - off] : 0;
        __syncthreads();
        sc[t] += add;
        __syncthreads();
    }
    int excl = sc[t] - run;
    #pragma unroll
    for (int j = 0; j < 8; ++j) {
        int idx = base + t * 8 + j;
        if (idx < NN) row_ptr[idx + 1] = excl + v[j];
    }
    if (t == 255) bsum[blockIdx.x] = sc[255];
}

// scan3 with inlined block-prefix of bsum (scan2 eliminated)
__global__ void k_scan3(int* row_ptr, const int* __restrict__ bsum) {
    int base = blockIdx.x * SCAN_CHUNK;
    int add = 0;
    for (int b = 0; b < (int)blockIdx.x; ++b) add += bsum[b];  // ≤48 wave-uniform adds
    if (blockIdx.x == 0 && threadIdx.x == 0) row_ptr[0] = 0;
    for (int j = threadIdx.x; j < SCAN_CHUNK; j += blockDim.x) {
        int idx = base + j;
        if (idx < NN) row_ptr[idx + 1] += add;
    }
}

// dst-range-partitioned scatter (XCD-local csr_src lines)
__global__ __launch_bounds__(256) void k_scatter(const int* __restrict__ ei,
                          const int* __restrict__ row_ptr,
                          int* cursor, int* __restrict__ csr_src) {
    int rng = blockIdx.x & (SC_RANGES - 1);
    int rlo = rng * SC_RSZ;
    int rhi = min(rlo + SC_RSZ, NN);
    int ch = blockIdx.x >> 3;
    for (int e = ch * 256 + threadIdx.x; e < EE; e += SC_CHUNKS * 256) {
        int d = (e < NE) ? ei[NE + e] : e - NE;
        if (d >= rlo && d < rhi) {
            int s = (e < NE) ? ei[e] : d;
            int slot = row_ptr[d] + atomicAdd(&cursor[d], 1);
            csr_src[slot] = s;
        }
    }
}

// ---------------- GAT aggregation: one wave per node, 4 edges/iteration (R7-proven) ----------------
// 16-lane group g streams edge (it*4+g); lane handles 8 dims (ushort8 = 16B).
__global__ __launch_bounds__(256) void k_gat_agg(
        const ushort* __restrict__ H, const float* __restrict__ as_,
        const float* __restrict__ ad_, const int* __restrict__ row_ptr,
        const int* __restrict__ csr_src, const float* __restrict__ bias,
        ushort* __restrict__ OUT) {
    int wid = (blockIdx.x * blockDim.x + threadIdx.x) >> 6;
    int lane = threadIdx.x & 63;
    if (wid >= NN) return;
    int grp = lane >> 4, l15 = lane & 15;
    int beg = row_ptr[wid], end = row_ptr[wid + 1];
    float adn = ad_[wid];
    float ssum = 0.f;
    float facc[8];
    #pragma unroll
    for (int d = 0; d < 8; ++d) facc[d] = 0.f;

    for (int cb = beg; cb < end; cb += 64) {
        int cn = min(64, end - cb);
        int s = 0;
        float w = 0.f;
        if (lane < cn) {
            s = csr_src[cb + lane];                     // coalesced
            w = __expf(lrelu(as_[s] + adn));            // parallel gather + exp
        }
        // wave-wide softmax denominator (out of the serial loop)
        float ws = w;
        #pragma unroll
        for (int o = 32; o > 0; o >>= 1) ws += __shfl_xor(ws, o);
        ssum += ws;

        int nIter = (cn + 3) >> 2;
        int sj = __shfl(s, grp);
        for (int it = 0; it < nIter; ++it) {
            u16x8 hv = *(const u16x8*)(H + (size_t)sj * DH + l15 * 8);
            int sn = __shfl(s, ((it + 1) * 4 + grp) & 63);   // prefetch next src idx
            float wj = __shfl(w, it * 4 + grp);              // 0 for tail edges
            #pragma unroll
            for (int d = 0; d < 8; ++d)
                facc[d] = fmaf(wj, bf2f(hv[d]), facc[d]);
            sj = sn;
        }
    }
    // cross-group reduce (groups 0..3 hold partials of the same dims)
    #pragma unroll
    for (int d = 0; d < 8; ++d) {
        facc[d] += __shfl_xor(facc[d], 16);
        facc[d] += __shfl_xor(facc[d], 32);
    }
    float inv = 1.0f / ssum;
    if (grp == 0) {
        u16x8 pk;
        #pragma unroll
        for (int d = 0; d < 8; ++d) {
            float o = fmaxf(fmaf(facc[d], inv, bias[l15 * 8 + d]), 0.f);
            pk[d] = f2bf(o);
        }
        *(u16x8*)(OUT + (size_t)wid * DH + l15 * 8) = pk;
    }
}

// ---------------- BatchNorm stats: per-block partials, no global atomics ----------------
__global__ __launch_bounds__(256) void k_bn_stats(const ushort* __restrict__ H,
                                                  float* __restrict__ partial) {
    __shared__ float rs[8][DH], rq[8][DH];   // 8 KB
    int t = threadIdx.x;
    int cg = (t & 31) * 4;   // col group of 4
    int rl = t >> 5;         // row lane 0..7
    float4 s = make_float4(0.f, 0.f, 0.f, 0.f);
    float4 q = make_float4(0.f, 0.f, 0.f, 0.f);
    for (int r = blockIdx.x * 8 + rl; r < NN; r += BNS_NB * 8) {
        ushort4 u = *(const ushort4*)(H + (size_t)r * DH + cg);
        float vx = bf2f(u.x), vy = bf2f(u.y), vz = bf2f(u.z), vw = bf2f(u.w);
        s.x += vx; q.x = fmaf(vx, vx, q.x);
        s.y += vy; q.y = fmaf(vy, vy, q.y);
        s.z += vz; q.z = fmaf(vz, vz, q.z);
        s.w += vw; q.w = fmaf(vw, vw, q.w);
    }
    *(float4*)(&rs[rl][cg]) = s;
    *(float4*)(&rq[rl][cg]) = q;
    __syncthreads();
    int c = t & 127;
    float acc = 0.f;
    if (t < 128) {
        #pragma unroll
        for (int i = 0; i < 8; ++i) acc += rs[i][c];
    } else {
        #pragma unroll
        for (int i = 0; i < 8; ++i) acc += rq[i][c];
    }
    partial[blockIdx.x * 256 + t] = acc;   // coalesced 1KB store per block
}

// reduce partials: 16 blocks x 256 thr (bn_sums/bn_sumsq zeroed via memset)
__global__ void k_bn_red(const float* __restrict__ partial,
                         float* bn_sums, float* bn_sumsq) {
    int t = threadIdx.x;
    float acc = 0.f;
    for (int b = blockIdx.x; b < BNS_NB; b += 16)
        acc += partial[b * 256 + t];
    if (t < 128) atomicAdd(&bn_sums[t], acc);
    else         atomicAdd(&bn_sumsq[t - 128], acc);
}

__global__ void k_bn_fin(const float* bn_sums, const float* bn_sumsq,
                         const float* __restrict__ g_, const float* __restrict__ b_,
                         float* scale, float* shift) {
    int c = threadIdx.x;  // 128
    float mu = bn_sums[c] / (float)NN;
    float var = bn_sumsq[c] / (float)NN - mu * mu;
    float sc = g_[c] * rsqrtf(var + BN_EPS);
    scale[c] = sc;
    shift[c] = fmaf(-mu, sc, b_[c]);
}

// fused BN-apply + relu + segment-mean-pool (batch sorted), bf16 H
__global__ __launch_bounds__(256) void k_bn_pool(const ushort* __restrict__ H,
                          const float* __restrict__ scale, const float* __restrict__ shift,
                          const int* __restrict__ batch, float* pool, float* cnt) {
    int t = threadIdx.x;
    int c2 = (t & 63) * 2;
    int rl = t >> 6;       // 0..3, wave-uniform
    int r0 = blockIdx.x * 128;
    if (r0 >= NN) return;
    int rend = min(r0 + 128, NN);
    float sc0 = scale[c2], sh0 = shift[c2];
    float sc1 = scale[c2 + 1], sh1 = shift[c2 + 1];
    float a0 = 0.f, a1 = 0.f, rcnt = 0.f;
    int curg = batch[min(r0 + rl, NN - 1)];
    for (int r = r0 + rl; r < rend; r += 4) {
        int g = batch[r];   // wave-uniform scalar load
        if (g != curg) {
            atomicAdd(&pool[curg * DH + c2], a0);
            atomicAdd(&pool[curg * DH + c2 + 1], a1);
            if ((t & 63) == 0) atomicAdd(&cnt[curg], rcnt);
            a0 = 0.f; a1 = 0.f; rcnt = 0.f; curg = g;
        }
        ushort2 u = *((const ushort2*)(H + (size_t)r * DH) + (t & 63));
        a0 += fmaxf(fmaf(bf2f(u.x), sc0, sh0), 0.f);
        a1 += fmaxf(fmaf(bf2f(u.y), sc1, sh1), 0.f);
        rcnt += 1.f;
    }
    atomicAdd(&pool[curg * DH + c2], a0);
    atomicAdd(&pool[curg * DH + c2 + 1], a1);
    if ((t & 63) == 0) atomicAdd(&cnt[curg], rcnt);
}

// ---------------- head (ILP-restructured) ----------------
__global__ __launch_bounds__(256) void k_head_docf(
        const float* __restrict__ docf, const float* __restrict__ doc_W,
        const float* __restrict__ doc_b, const float* __restrict__ pool,
        const float* __restrict__ cnt, float* __restrict__ f) {
    __shared__ float4 red[8][32];   // 4 KB
    int g = blockIdx.x;   // 64
    int t = threadIdx.x;  // 256
    int cq = t & 31, kq = t >> 5;
    const float* dr = docf + g * DDOC;
    float4 acc = make_float4(0.f, 0.f, 0.f, 0.f);
    #pragma unroll 8
    for (int i = 0; i < 32; ++i) {
        int k = kq + i * 8;
        float dv = dr[k];
        float4 w = *(const float4*)(doc_W + k * DH + cq * 4);
        acc.x = fmaf(dv, w.x, acc.x);
        acc.y = fmaf(dv, w.y, acc.y);
        acc.z = fmaf(dv, w.z, acc.z);
        acc.w = fmaf(dv, w.w, acc.w);
    }
    red[kq][cq] = acc;
    __syncthreads();
    if (t < 32) {
        float4 s = red[0][t];
        #pragma unroll
        for (int i = 1; i < 8; ++i) {
            float4 a = red[i][t];
            s.x += a.x; s.y += a.y; s.z += a.z; s.w += a.w;
        }
        float4 b4 = *(const float4*)(doc_b + t * 4);
        s.x = fmaxf(s.x + b4.x, 0.f);
        s.y = fmaxf(s.y + b4.y, 0.f);
        s.z = fmaxf(s.z + b4.z, 0.f);
        s.w = fmaxf(s.w + b4.w, 0.f);
        *(float4*)(f + g * 2 * DH + DH + t * 4) = s;
    } else if (t >= 128) {
        int c = t - 128;
        f[g * 2 * DH + c] = pool[g * DH + c] / fmaxf(cnt[g], 1.0f);
    }
}

__global__ void k_head_bnf(const float* __restrict__ f, const float* __restrict__ g_,
                           const float* __restrict__ b_, float* __restrict__ fn) {
    int c = threadIdx.x;  // 256
    float s = 0.f, q = 0.f;
    #pragma unroll 16
    for (int r = 0; r < NG; ++r) {
        float v = f[r * 2 * DH + c];
        s += v; q = fmaf(v, v, q);
    }
    float mu = s / (float)NG;
    float var = q / (float)NG - mu * mu;
    float sc = g_[c] * rsqrtf(var + BN_EPS);
    float sh = fmaf(-mu, sc, b_[c]);
    #pragma unroll 16
    for (int r = 0; r < NG; ++r)
        fn[r * 2 * DH + c] = fmaf(f[r * 2 * DH + c], sc, sh);
}

__global__ __launch_bounds__(256) void k_head_out(
        const float* __restrict__ fn, const float* __restrict__ fus_W,
        const float* __restrict__ fus_b, const float* __restrict__ task_W,
        const float* __restrict__ task_b, const float* __restrict__ time_W,
        const float* __restrict__ time_b, float* __restrict__ out) {
    __shared__ float4 red[8][32];   // 4 KB (reused by stage 2 as [16][16])
    __shared__ float ff[DH];
    int g = blockIdx.x;   // 64
    int t = threadIdx.x;  // 256
    const float* fr = fn + g * 2 * DH;
    {
        int cq = t & 31, kq = t >> 5;
        float4 acc = make_float4(0.f, 0.f, 0.f, 0.f);
        #pragma unroll 8
        for (int i = 0; i < 32; ++i) {
            int k = kq + i * 8;
            float fv = fr[k];
            float4 w = *(const float4*)(fus_W + k * DH + cq * 4);
            acc.x = fmaf(fv, w.x, acc.x);
            acc.y = fmaf(fv, w.y, acc.y);
            acc.z = fmaf(fv, w.z, acc.z);
            acc.w = fmaf(fv, w.w, acc.w);
        }
        red[kq][cq] = acc;
    }
    __syncthreads();
    if (t < 32) {
        float4 s = red[0][t];
        #pragma unroll
        for (int i = 1; i < 8; ++i) {
            float4 a = red[i][t];
            s.x += a.x; s.y += a.y; s.z += a.z; s.w += a.w;
        }
        float4 b4 = *(const float4*)(fus_b + t * 4);
        ff[t * 4 + 0] = fmaxf(s.x + b4.x, 0.f);
        ff[t * 4 + 1] = fmaxf(s.y + b4.y, 0.f);
        ff[t * 4 + 2] = fmaxf(s.z + b4.z, 0.f);
        ff[t * 4 + 3] = fmaxf(s.w + b4.w, 0.f);
    }
    __syncthreads();
    {
        int cq = t & 15, kq = t >> 4;
        float4 acc = make_float4(0.f, 0.f, 0.f, 0.f);
        #pragma unroll
        for (int i = 0; i < 8; ++i) {
            int k = kq + i * 16;
            float fv = ff[k];
            float4 w = *(const float4*)(task_W + k * DOUT + cq * 4);
            acc.x = fmaf(fv, w.x, acc.x);
            acc.y = fmaf(fv, w.y, acc.y);
            acc.z = fmaf(fv, w.z, acc.z);
            acc.w = fmaf(fv, w.w, acc.w);
        }
        float4* red2 = (float4*)red;
        red2[kq * 16 + cq] = acc;
    }
    float tp = 0.f;
    if (t >= 64 && t < 128) {
        int k = t - 64;
        tp = fmaf(ff[k], time_W[k], ff[k + 64] * time_W[k + 64]);
    }
    __syncthreads();
    if (t < 16) {
        const float4* red2 = (const float4*)red;
        float4 s = red2[t];
        #pragma unroll
        for (int i = 1; i < 16; ++i) {
            float4 a = red2[i * 16 + t];
            s.x += a.x; s.y += a.y; s.z += a.z; s.w += a.w;
        }
        float4 b4 = *(const float4*)(task_b + t * 4);
        s.x += b4.x; s.y += b4.y; s.z += b4.z; s.w += b4.w;
        *(float4*)(out + g * DOUT + t * 4) = s;
    }
    if (t >= 64 && t < 128) {
        #pragma unroll
        for (int o = 32; o > 0; o >>= 1) tp += __shfl_xor(tp, o);
        if (t == 64) out[NG * DOUT + g] = tp + time_b[0];
    }
}

extern "C" void kernel_launch(void* const* d_in, const int* in_sizes, int n_in,
                              void* d_out, int out_size, void* d_ws, size_t ws_size,
                              hipStream_t stream) {
    const float* x      = (const float*)d_in[0];
    const int*   ei     = (const int*)d_in[1];
    const int*   batch  = (const int*)d_in[2];
    const float* docf   = (const float*)d_in[3];
    const float* W1     = (const float*)d_in[4];
    const float* a_src1 = (const float*)d_in[5];
    const float* a_dst1 = (const float*)d_in[6];
    const float* b1     = (const float*)d_in[7];
    const float* W2     = (const float*)d_in[8];
    const float* a_src2 = (const float*)d_in[9];
    const float* a_dst2 = (const float*)d_in[10];
    const float* b2     = (const float*)d_in[11];
    const float* bn2_g  = (const float*)d_in[12];
    const float* bn2_b  = (const float*)d_in[13];
    const float* doc_W  = (const float*)d_in[14];
    const float* doc_b  = (const float*)d_in[15];
    const float* bnf_g  = (const float*)d_in[16];
    const float* bnf_b  = (const float*)d_in[17];
    const float* fus_W  = (const float*)d_in[18];
    const float* fus_b  = (const float*)d_in[19];
    const float* task_W = (const float*)d_in[20];
    const float* task_b = (const float*)d_in[21];
    const float* time_W = (const float*)d_in[22];
    const float* time_b = (const float*)d_in[23];
    float* out = (float*)d_out;

    char* p = (char*)d_ws;
    size_t off = 0;
    auto alloc = [&](size_t bytes) {
        void* r = p + off;
        off += (bytes + 255) & ~(size_t)255;
        return r;
    };
    ushort* hA     = (ushort*)alloc((size_t)NN * DH * 2);  // GEMM out (bf16)
    ushort* hB     = (ushort*)alloc((size_t)NN * DH * 2);  // agg out (bf16)
    float* as_     = (float*)alloc(NN * 4);
    float* ad_     = (float*)alloc(NN * 4);
    int*   row_ptr = (int*)  alloc((NN + 1) * 4);
    // zero-region 1: counts | cursor | bn_sums | bn_sumsq (one memset)
    int*   counts  = (int*)  alloc((2 * NN + 2 * DH) * 4);
    int*   cursor  = counts + NN;
    float* bn_sums = (float*)(cursor + NN);
    float* bn_sumsq= bn_sums + DH;
    int*   csr_src = (int*)  alloc((size_t)EE * 4);
    int*   bsum    = (int*)  alloc(SCAN_NB * 4);
    float* scale   = (float*)alloc(DH * 4);
    float* shift   = (float*)alloc(DH * 4);
    // zero-region 2: pool | cnt (one memset)
    float* pool    = (float*)alloc((NG * DH + NG) * 4);
    float* cnt     = pool + NG * DH;
    float* f       = (float*)alloc(NG * 2 * DH * 4);
    float* fnrm    = (float*)alloc(NG * 2 * DH * 4);
    ushort* Wp1    = (ushort*)alloc(16384 * 2);
    ushort* Wp2    = (ushort*)alloc(16384 * 2);
    float* bn_part = (float*)alloc((size_t)BNS_NB * 256 * 4);  // 512 KB
    (void)ws_size; (void)in_sizes; (void)n_in; (void)out_size;

    auto cdiv = [](int a, int b) { return (a + b - 1) / b; };

    hipMemsetAsync(counts, 0, (size_t)(2 * NN + 2 * DH) * 4, stream);
    hipMemsetAsync(pool, 0, (size_t)(NG * DH + NG) * 4, stream);

    // W pre-pack + histogram (merged); CSR build (shared by both layers)
    k_wpack_hist<<<2 + cdiv(NE, 256), 256, 0, stream>>>(W1, W2, Wp1, Wp2, ei, counts);
    k_scan1<<<SCAN_NB, 256, 0, stream>>>(counts, row_ptr, bsum);
    k_scan3<<<SCAN_NB, 256, 0, stream>>>(row_ptr, bsum);
    k_scatter<<<SC_RANGES * SC_CHUNKS, 256, 0, stream>>>(ei, row_ptr, cursor, csr_src);

    // GAT layer 1
    k_gemm_att<false><<<cdiv(NN, GR), 256, 0, stream>>>(x, Wp1, a_src1, a_dst1, hA, as_, ad_, NN);
    k_gat_agg<<<cdiv(NN, 4), 256, 0, stream>>>(hA, as_, ad_, row_ptr, csr_src, b1, hB);

    // GAT layer 2 (input hB is bf16)
    k_gemm_att<true><<<cdiv(NN, GR), 256, 0, stream>>>(hB, Wp2, a_src2, a_dst2, hA, as_, ad_, NN);
    k_gat_agg<<<cdiv(NN, 4), 256, 0, stream>>>(hA, as_, ad_, row_ptr, csr_src, b2, hB);

    // BN + relu + mean-pool
    k_bn_stats<<<BNS_NB, 256, 0, stream>>>(hB, bn_part);
    k_bn_red<<<16, 256, 0, stream>>>(bn_part, bn_sums, bn_sumsq);
    k_bn_fin<<<1, 128, 0, stream>>>(bn_sums, bn_sumsq, bn2_g, bn2_b, scale, shift);
    k_bn_pool<<<cdiv(NN, 128), 256, 0, stream>>>(hB, scale, shift, batch, pool, cnt);

    // head
    k_head_docf<<<NG, 256, 0, stream>>>(docf, doc_W, doc_b, pool, cnt, f);
    k_head_bnf<<<1, 256, 0, stream>>>(f, bnf_g, bnf_b, fnrm);
    k_head_out<<<NG, 256, 0, stream>>>(fnrm, fus_W, fus_b, task_W, task_b, time_W, time_b, out);
}

// Round 12
// 304.824 us; speedup vs baseline: 1.0281x; 1.0088x over previous
//
#include <hip/hip_runtime.h>
#include <hip/hip_bf16.h>

#define NN 100000
#define NE 800000
#define EE 900000   // NE + NN self loops
#define NG 64
#define DH 128
#define DDOC 256
#define DOUT 64
#define BN_EPS 1e-5f
#define SLOPE 0.2f
#define SCAN_CHUNK 2048
#define SCAN_NB ((NN + SCAN_CHUNK - 1) / SCAN_CHUNK)
#define GR 64      // GEMM rows per block
#define BNS_NB 512 // bn_stats blocks
#define SC_RANGES 8
#define SC_RSZ ((NN + SC_RANGES - 1) / SC_RANGES)  // 12500
#define SC_CHUNKS 128

typedef __attribute__((ext_vector_type(8))) short bf16x8;
typedef __attribute__((ext_vector_type(8))) unsigned short u16x8;
typedef __attribute__((ext_vector_type(4))) float f32x4;

__device__ __forceinline__ float lrelu(float x) { return x > 0.f ? x : SLOPE * x; }

// f32 -> bf16 (round to nearest even)
__device__ __forceinline__ ushort f2bf(float f) {
    union { float f; unsigned u; } v; v.f = f;
    unsigned u = v.u;
    unsigned r = (u + 0x7fffu + ((u >> 16) & 1u)) >> 16;
    return (ushort)r;
}
__device__ __forceinline__ float bf2f(ushort u) {
    union { unsigned u; float f; } v; v.u = ((unsigned)u) << 16;
    return v.f;
}

// ---------------- merged W pre-pack (blocks 0-1) + edge histogram (blocks 2+) ----------------
__global__ void k_wpack_hist(const float* __restrict__ W1, const float* __restrict__ W2,
                             ushort* __restrict__ P1, ushort* __restrict__ P2,
                             const int* __restrict__ ei, int* counts) {
    if (blockIdx.x < 2) {
        const float* W = blockIdx.x ? W2 : W1;
        ushort* P = blockIdx.x ? P2 : P1;
        for (int idx = threadIdx.x; idx < 16384; idx += 256) {
            int j = idx & 7;
            int lane = (idx >> 3) & 63;
            int kc = idx >> 9;             // 0..31
            int ct = kc & 7, k = kc >> 3;
            int kk = k * 32 + ((lane >> 4) * 8) + j;
            int col = ct * 16 + (lane & 15);
            P[idx] = f2bf(W[kk * 128 + col]);
        }
    } else {
        int e = (blockIdx.x - 2) * 256 + threadIdx.x;
        if (e < NE) atomicAdd(&counts[ei[NE + e]], 1);
    }
}

// ---------------- fused MFMA GEMM + attention dots ----------------
// H (bf16) = X @ W ; as_/ad_ from f32 accumulators. Coalesced H store via LDS repack.
template <bool BF16IN>
__global__ __launch_bounds__(256) void k_gemm_att(
        const void* __restrict__ Xv, const ushort* __restrict__ Wp,
        const float* __restrict__ a_s, const float* __restrict__ a_d,
        ushort* __restrict__ H, float* __restrict__ as_, float* __restrict__ ad_,
        int nrows) {
    __shared__ ushort As[GR * DH];   // 16 KB, XOR-swizzled rows (byte ^= (row&7)<<4)
    int t = threadIdx.x;
    int wv = t >> 6, lane = t & 63;
    int g = lane >> 4, l15 = lane & 15;
    int r0 = blockIdx.x * GR;
    if constexpr (BF16IN) {
        const ushort* X = (const ushort*)Xv;
        #pragma unroll
        for (int i = 0; i < 4; ++i) {
            int row = i * 16 + (t >> 4);
            int col = (t & 15) * 8;
            int gr = r0 + row;
            bf16x8 v = (bf16x8){0, 0, 0, 0, 0, 0, 0, 0};
            if (gr < nrows) v = *(const bf16x8*)(X + (size_t)gr * DH + col);
            int boff = row * 256 + ((col * 2) ^ ((row & 7) << 4));
            *(bf16x8*)((char*)As + boff) = v;
        }
    } else {
        const float* X = (const float*)Xv;
        #pragma unroll
        for (int i = 0; i < 8; ++i) {
            int row = i * 8 + (t >> 5);
            int col = (t & 31) * 4;
            int gr = r0 + row;
            float4 v = (gr < nrows) ? *(const float4*)(X + (size_t)gr * DH + col)
                                    : make_float4(0.f, 0.f, 0.f, 0.f);
            ushort4 pk;
            pk.x = f2bf(v.x); pk.y = f2bf(v.y); pk.z = f2bf(v.z); pk.w = f2bf(v.w);
            int boff = row * 256 + ((col * 2) ^ ((row & 7) << 4));
            *(ushort4*)((char*)As + boff) = pk;
        }
    }
    __syncthreads();

    f32x4 acc[8];
    #pragma unroll
    for (int ct = 0; ct < 8; ++ct) acc[ct] = (f32x4){0.f, 0.f, 0.f, 0.f};
    int arow = wv * 16 + l15;
    int abase = arow * 256;
    int aswz = (arow & 7) << 4;
    #pragma unroll
    for (int k = 0; k < 4; ++k) {
        bf16x8 a = *(const bf16x8*)((const char*)As + abase + ((k * 64 + g * 16) ^ aswz));
        #pragma unroll
        for (int ct = 0; ct < 8; ++ct) {
            bf16x8 b = *(const bf16x8*)(Wp + (((k * 8 + ct) * 64 + lane) << 3));
            acc[ct] = __builtin_amdgcn_mfma_f32_16x16x32_bf16(a, b, acc[ct], 0, 0, 0);
        }
    }

    // attention dots from registers (row fully wave-local)
    float asv[8], adv[8];
    #pragma unroll
    for (int ct = 0; ct < 8; ++ct) {
        asv[ct] = a_s[ct * 16 + l15];
        adv[ct] = a_d[ct * 16 + l15];
    }
    int rbase = r0 + wv * 16 + g * 4;
    #pragma unroll
    for (int r = 0; r < 4; ++r) {
        int gr = rbase + r;
        bool ok = gr < nrows;
        float ps = 0.f, pd = 0.f;
        #pragma unroll
        for (int ct = 0; ct < 8; ++ct) {
            float v = acc[ct][r];
            ps = fmaf(v, asv[ct], ps);
            pd = fmaf(v, adv[ct], pd);
        }
        ps += __shfl_xor(ps, 1); pd += __shfl_xor(pd, 1);
        ps += __shfl_xor(ps, 2); pd += __shfl_xor(pd, 2);
        ps += __shfl_xor(ps, 4); pd += __shfl_xor(pd, 4);
        ps += __shfl_xor(ps, 8); pd += __shfl_xor(pd, 8);
        if (ok && l15 == 0) { as_[gr] = ps; ad_[gr] = pd; }
    }

    // H store: repack acc through LDS (As now free), then coalesced 16B stores
    __syncthreads();   // all waves done reading As in their k-loops
    #pragma unroll
    for (int r = 0; r < 4; ++r) {
        int lrow = wv * 16 + g * 4 + r;   // 0..63
        #pragma unroll
        for (int ct = 0; ct < 8; ++ct) {
            int boff = (lrow * 256 + (ct * 16 + l15) * 2) ^ ((lrow & 7) << 4);
            *(ushort*)((char*)As + boff) = f2bf(acc[ct][r]);
        }
    }
    __syncthreads();
    #pragma unroll
    for (int i = 0; i < 4; ++i) {
        int chunk = i * 256 + t;          // 0..1023 sixteen-byte chunks
        int row = chunk >> 4;
        int c8 = (chunk & 15) * 8;        // col start (8 ushorts)
        int gr = r0 + row;
        if (gr < nrows) {
            int boff = (row * 256 + c8 * 2) ^ ((row & 7) << 4);
            *(u16x8*)(H + (size_t)gr * DH + c8) = *(const u16x8*)((const char*)As + boff);
        }
    }
}

// ---------------- CSR build ----------------
// scan1: prefix of (counts[i] + 1) — the +1 folds in the self loop (counts start at 0)
__global__ void k_scan1(const int* __restrict__ counts, int* __restrict__ row_ptr,
                        int* __restrict__ bsum) {
    __shared__ int sc[256];
    int t = threadIdx.x;
    int base = blockIdx.x * SCAN_CHUNK;
    int v[8];
    int run = 0;
    #pragma unroll
    for (int j = 0; j < 8; ++j) {
        int idx = base + t * 8 + j;
        int x = (idx < NN) ? counts[idx] + 1 : 0;
        run += x; v[j] = run;
    }
    sc[t] = run;
    __syncthreads();
    for (int off = 1; off < 256; off <<= 1) {
        int add = (t >= off) ? sc[t - off] : 0;
        __syncthreads();
        sc[t] += add;
        __syncthreads();
    }
    int excl = sc[t] - run;
    #pragma unroll
    for (int j = 0; j < 8; ++j) {
        int idx = base + t * 8 + j;
        if (idx < NN) row_ptr[idx + 1] = excl + v[j];
    }
    if (t == 255) bsum[blockIdx.x] = sc[255];
}

// scan3 with inlined block-prefix of bsum (scan2 eliminated)
__global__ void k_scan3(int* row_ptr, const int* __restrict__ bsum) {
    int base = blockIdx.x * SCAN_CHUNK;
    int add = 0;
    for (int b = 0; b < (int)blockIdx.x; ++b) add += bsum[b];  // ≤48 wave-uniform adds
    if (blockIdx.x == 0 && threadIdx.x == 0) row_ptr[0] = 0;
    for (int j = threadIdx.x; j < SCAN_CHUNK; j += blockDim.x) {
        int idx = base + j;
        if (idx < NN) row_ptr[idx + 1] += add;
    }
}

// dst-range-partitioned scatter (XCD-local csr_src lines)
__global__ __launch_bounds__(256) void k_scatter(const int* __restrict__ ei,
                          const int* __restrict__ row_ptr,
                          int* cursor, int* __restrict__ csr_src) {
    int rng = blockIdx.x & (SC_RANGES - 1);
    int rlo = rng * SC_RSZ;
    int rhi = min(rlo + SC_RSZ, NN);
    int ch = blockIdx.x >> 3;
    for (int e = ch * 256 + threadIdx.x; e < EE; e += SC_CHUNKS * 256) {
        int d = (e < NE) ? ei[NE + e] : e - NE;
        if (d >= rlo && d < rhi) {
            int s = (e < NE) ? ei[e] : d;
            int slot = row_ptr[d] + atomicAdd(&cursor[d], 1);
            csr_src[slot] = s;
        }
    }
}

// ---------------- GAT aggregation: one wave per node, 4 edges/iteration (proven floor) ----------------
__global__ __launch_bounds__(256) void k_gat_agg(
        const ushort* __restrict__ H, const float* __restrict__ as_,
        const float* __restrict__ ad_, const int* __restrict__ row_ptr,
        const int* __restrict__ csr_src, const float* __restrict__ bias,
        ushort* __restrict__ OUT) {
    int wid = (blockIdx.x * blockDim.x + threadIdx.x) >> 6;
    int lane = threadIdx.x & 63;
    if (wid >= NN) return;
    int grp = lane >> 4, l15 = lane & 15;
    int beg = row_ptr[wid], end = row_ptr[wid + 1];
    float adn = ad_[wid];
    float ssum = 0.f;
    float facc[8];
    #pragma unroll
    for (int d = 0; d < 8; ++d) facc[d] = 0.f;

    for (int cb = beg; cb < end; cb += 64) {
        int cn = min(64, end - cb);
        int s = 0;
        float w = 0.f;
        if (lane < cn) {
            s = csr_src[cb + lane];                     // coalesced
            w = __expf(lrelu(as_[s] + adn));            // parallel gather + exp
        }
        float ws = w;
        #pragma unroll
        for (int o = 32; o > 0; o >>= 1) ws += __shfl_xor(ws, o);
        ssum += ws;

        int nIter = (cn + 3) >> 2;
        int sj = __shfl(s, grp);
        for (int it = 0; it < nIter; ++it) {
            u16x8 hv = *(const u16x8*)(H + (size_t)sj * DH + l15 * 8);
            int sn = __shfl(s, ((it + 1) * 4 + grp) & 63);
            float wj = __shfl(w, it * 4 + grp);
            #pragma unroll
            for (int d = 0; d < 8; ++d)
                facc[d] = fmaf(wj, bf2f(hv[d]), facc[d]);
            sj = sn;
        }
    }
    #pragma unroll
    for (int d = 0; d < 8; ++d) {
        facc[d] += __shfl_xor(facc[d], 16);
        facc[d] += __shfl_xor(facc[d], 32);
    }
    float inv = 1.0f / ssum;
    if (grp == 0) {
        u16x8 pk;
        #pragma unroll
        for (int d = 0; d < 8; ++d) {
            float o = fmaxf(fmaf(facc[d], inv, bias[l15 * 8 + d]), 0.f);
            pk[d] = f2bf(o);
        }
        *(u16x8*)(OUT + (size_t)wid * DH + l15 * 8) = pk;
    }
}

// ---------------- BatchNorm stats: per-block partials, no global atomics ----------------
__global__ __launch_bounds__(256) void k_bn_stats(const ushort* __restrict__ H,
                                                  float* __restrict__ partial) {
    __shared__ float rs[8][DH], rq[8][DH];   // 8 KB
    int t = threadIdx.x;
    int cg = (t & 31) * 4;
    int rl = t >> 5;
    float4 s = make_float4(0.f, 0.f, 0.f, 0.f);
    float4 q = make_float4(0.f, 0.f, 0.f, 0.f);
    for (int r = blockIdx.x * 8 + rl; r < NN; r += BNS_NB * 8) {
        ushort4 u = *(const ushort4*)(H + (size_t)r * DH + cg);
        float vx = bf2f(u.x), vy = bf2f(u.y), vz = bf2f(u.z), vw = bf2f(u.w);
        s.x += vx; q.x = fmaf(vx, vx, q.x);
        s.y += vy; q.y = fmaf(vy, vy, q.y);
        s.z += vz; q.z = fmaf(vz, vz, q.z);
        s.w += vw; q.w = fmaf(vw, vw, q.w);
    }
    *(float4*)(&rs[rl][cg]) = s;
    *(float4*)(&rq[rl][cg]) = q;
    __syncthreads();
    int c = t & 127;
    float acc = 0.f;
    if (t < 128) {
        #pragma unroll
        for (int i = 0; i < 8; ++i) acc += rs[i][c];
    } else {
        #pragma unroll
        for (int i = 0; i < 8; ++i) acc += rq[i][c];
    }
    partial[blockIdx.x * 256 + t] = acc;
}

// reduce partials: 16 blocks x 256 thr (bn_sums/bn_sumsq zeroed via memset)
__global__ void k_bn_red(const float* __restrict__ partial,
                         float* bn_sums, float* bn_sumsq) {
    int t = threadIdx.x;
    float acc = 0.f;
    for (int b = blockIdx.x; b < BNS_NB; b += 16)
        acc += partial[b * 256 + t];
    if (t < 128) atomicAdd(&bn_sums[t], acc);
    else         atomicAdd(&bn_sumsq[t - 128], acc);
}

// fused BN-finalize + apply + relu + segment-mean-pool (batch sorted), bf16 H
// scale/shift recomputed per block from bn_sums (512B, L2-hot) — k_bn_fin eliminated
__global__ __launch_bounds__(256) void k_bn_pool(const ushort* __restrict__ H,
                          const float* __restrict__ bn_sums, const float* __restrict__ bn_sumsq,
                          const float* __restrict__ g_, const float* __restrict__ b_,
                          const int* __restrict__ batch, float* pool, float* cnt) {
    int t = threadIdx.x;
    int c2 = (t & 63) * 2;
    int rl = t >> 6;       // 0..3, wave-uniform
    int r0 = blockIdx.x * 128;
    if (r0 >= NN) return;
    int rend = min(r0 + 128, NN);
    float mu0 = bn_sums[c2] / (float)NN;
    float mu1 = bn_sums[c2 + 1] / (float)NN;
    float var0 = bn_sumsq[c2] / (float)NN - mu0 * mu0;
    float var1 = bn_sumsq[c2 + 1] / (float)NN - mu1 * mu1;
    float sc0 = g_[c2] * rsqrtf(var0 + BN_EPS);
    float sc1 = g_[c2 + 1] * rsqrtf(var1 + BN_EPS);
    float sh0 = fmaf(-mu0, sc0, b_[c2]);
    float sh1 = fmaf(-mu1, sc1, b_[c2 + 1]);
    float a0 = 0.f, a1 = 0.f, rcnt = 0.f;
    int curg = batch[min(r0 + rl, NN - 1)];
    for (int r = r0 + rl; r < rend; r += 4) {
        int g = batch[r];   // wave-uniform scalar load
        if (g != curg) {
            atomicAdd(&pool[curg * DH + c2], a0);
            atomicAdd(&pool[curg * DH + c2 + 1], a1);
            if ((t & 63) == 0) atomicAdd(&cnt[curg], rcnt);
            a0 = 0.f; a1 = 0.f; rcnt = 0.f; curg = g;
        }
        ushort2 u = *((const ushort2*)(H + (size_t)r * DH) + (t & 63));
        a0 += fmaxf(fmaf(bf2f(u.x), sc0, sh0), 0.f);
        a1 += fmaxf(fmaf(bf2f(u.y), sc1, sh1), 0.f);
        rcnt += 1.f;
    }
    atomicAdd(&pool[curg * DH + c2], a0);
    atomicAdd(&pool[curg * DH + c2 + 1], a1);
    if ((t & 63) == 0) atomicAdd(&cnt[curg], rcnt);
}

// ---------------- head (ILP-restructured) ----------------
__global__ __launch_bounds__(256) void k_head_docf(
        const float* __restrict__ docf, const float* __restrict__ doc_W,
        const float* __restrict__ doc_b, const float* __restrict__ pool,
        const float* __restrict__ cnt, float* __restrict__ f) {
    __shared__ float4 red[8][32];   // 4 KB
    int g = blockIdx.x;   // 64
    int t = threadIdx.x;  // 256
    int cq = t & 31, kq = t >> 5;
    const float* dr = docf + g * DDOC;
    float4 acc = make_float4(0.f, 0.f, 0.f, 0.f);
    #pragma unroll 8
    for (int i = 0; i < 32; ++i) {
        int k = kq + i * 8;
        float dv = dr[k];
        float4 w = *(const float4*)(doc_W + k * DH + cq * 4);
        acc.x = fmaf(dv, w.x, acc.x);
        acc.y = fmaf(dv, w.y, acc.y);
        acc.z = fmaf(dv, w.z, acc.z);
        acc.w = fmaf(dv, w.w, acc.w);
    }
    red[kq][cq] = acc;
    __syncthreads();
    if (t < 32) {
        float4 s = red[0][t];
        #pragma unroll
        for (int i = 1; i < 8; ++i) {
            float4 a = red[i][t];
            s.x += a.x; s.y += a.y; s.z += a.z; s.w += a.w;
        }
        float4 b4 = *(const float4*)(doc_b + t * 4);
        s.x = fmaxf(s.x + b4.x, 0.f);
        s.y = fmaxf(s.y + b4.y, 0.f);
        s.z = fmaxf(s.z + b4.z, 0.f);
        s.w = fmaxf(s.w + b4.w, 0.f);
        *(float4*)(f + g * 2 * DH + DH + t * 4) = s;
    } else if (t >= 128) {
        int c = t - 128;
        f[g * 2 * DH + c] = pool[g * DH + c] / fmaxf(cnt[g], 1.0f);
    }
}

__global__ void k_head_bnf(const float* __restrict__ f, const float* __restrict__ g_,
                           const float* __restrict__ b_, float* __restrict__ fn) {
    int c = threadIdx.x;  // 256
    float s = 0.f, q = 0.f;
    #pragma unroll 16
    for (int r = 0; r < NG; ++r) {
        float v = f[r * 2 * DH + c];
        s += v; q = fmaf(v, v, q);
    }
    float mu = s / (float)NG;
    float var = q / (float)NG - mu * mu;
    float sc = g_[c] * rsqrtf(var + BN_EPS);
    float sh = fmaf(-mu, sc, b_[c]);
    #pragma unroll 16
    for (int r = 0; r < NG; ++r)
        fn[r * 2 * DH + c] = fmaf(f[r * 2 * DH + c], sc, sh);
}

__global__ __launch_bounds__(256) void k_head_out(
        const float* __restrict__ fn, const float* __restrict__ fus_W,
        const float* __restrict__ fus_b, const float* __restrict__ task_W,
        const float* __restrict__ task_b, const float* __restrict__ time_W,
        const float* __restrict__ time_b, float* __restrict__ out) {
    __shared__ float4 red[8][32];   // 4 KB (reused by stage 2 as [16][16])
    __shared__ float ff[DH];
    int g = blockIdx.x;   // 64
    int t = threadIdx.x;  // 256
    const float* fr = fn + g * 2 * DH;
    {
        int cq = t & 31, kq = t >> 5;
        float4 acc = make_float4(0.f, 0.f, 0.f, 0.f);
        #pragma unroll 8
        for (int i = 0; i < 32; ++i) {
            int k = kq + i * 8;
            float fv = fr[k];
            float4 w = *(const float4*)(fus_W + k * DH + cq * 4);
            acc.x = fmaf(fv, w.x, acc.x);
            acc.y = fmaf(fv, w.y, acc.y);
            acc.z = fmaf(fv, w.z, acc.z);
            acc.w = fmaf(fv, w.w, acc.w);
        }
        red[kq][cq] = acc;
    }
    __syncthreads();
    if (t < 32) {
        float4 s = red[0][t];
        #pragma unroll
        for (int i = 1; i < 8; ++i) {
            float4 a = red[i][t];
            s.x += a.x; s.y += a.y; s.z += a.z; s.w += a.w;
        }
        float4 b4 = *(const float4*)(fus_b + t * 4);
        ff[t * 4 + 0] = fmaxf(s.x + b4.x, 0.f);
        ff[t * 4 + 1] = fmaxf(s.y + b4.y, 0.f);
        ff[t * 4 + 2] = fmaxf(s.z + b4.z, 0.f);
        ff[t * 4 + 3] = fmaxf(s.w + b4.w, 0.f);
    }
    __syncthreads();
    {
        int cq = t & 15, kq = t >> 4;
        float4 acc = make_float4(0.f, 0.f, 0.f, 0.f);
        #pragma unroll
        for (int i = 0; i < 8; ++i) {
            int k = kq + i * 16;
            float fv = ff[k];
            float4 w = *(const float4*)(task_W + k * DOUT + cq * 4);
            acc.x = fmaf(fv, w.x, acc.x);
            acc.y = fmaf(fv, w.y, acc.y);
            acc.z = fmaf(fv, w.z, acc.z);
            acc.w = fmaf(fv, w.w, acc.w);
        }
        float4* red2 = (float4*)red;
        red2[kq * 16 + cq] = acc;
    }
    float tp = 0.f;
    if (t >= 64 && t < 128) {
        int k = t - 64;
        tp = fmaf(ff[k], time_W[k], ff[k + 64] * time_W[k + 64]);
    }
    __syncthreads();
    if (t < 16) {
        const float4* red2 = (const float4*)red;
        float4 s = red2[t];
        #pragma unroll
        for (int i = 1; i < 16; ++i) {
            float4 a = red2[i * 16 + t];
            s.x += a.x; s.y += a.y; s.z += a.z; s.w += a.w;
        }
        float4 b4 = *(const float4*)(task_b + t * 4);
        s.x += b4.x; s.y += b4.y; s.z += b4.z; s.w += b4.w;
        *(float4*)(out + g * DOUT + t * 4) = s;
    }
    if (t >= 64 && t < 128) {
        #pragma unroll
        for (int o = 32; o > 0; o >>= 1) tp += __shfl_xor(tp, o);
        if (t == 64) out[NG * DOUT + g] = tp + time_b[0];
    }
}

extern "C" void kernel_launch(void* const* d_in, const int* in_sizes, int n_in,
                              void* d_out, int out_size, void* d_ws, size_t ws_size,
                              hipStream_t stream) {
    const float* x      = (const float*)d_in[0];
    const int*   ei     = (const int*)d_in[1];
    const int*   batch  = (const int*)d_in[2];
    const float* docf   = (const float*)d_in[3];
    const float* W1     = (const float*)d_in[4];
    const float* a_src1 = (const float*)d_in[5];
    const float* a_dst1 = (const float*)d_in[6];
    const float* b1     = (const float*)d_in[7];
    const float* W2     = (const float*)d_in[8];
    const float* a_src2 = (const float*)d_in[9];
    const float* a_dst2 = (const float*)d_in[10];
    const float* b2     = (const float*)d_in[11];
    const float* bn2_g  = (const float*)d_in[12];
    const float* bn2_b  = (const float*)d_in[13];
    const float* doc_W  = (const float*)d_in[14];
    const float* doc_b  = (const float*)d_in[15];
    const float* bnf_g  = (const float*)d_in[16];
    const float* bnf_b  = (const float*)d_in[17];
    const float* fus_W  = (const float*)d_in[18];
    const float* fus_b  = (const float*)d_in[19];
    const float* task_W = (const float*)d_in[20];
    const float* task_b = (const float*)d_in[21];
    const float* time_W = (const float*)d_in[22];
    const float* time_b = (const float*)d_in[23];
    float* out = (float*)d_out;

    char* p = (char*)d_ws;
    size_t off = 0;
    auto alloc = [&](size_t bytes) {
        void* r = p + off;
        off += (bytes + 255) & ~(size_t)255;
        return r;
    };
    ushort* hA     = (ushort*)alloc((size_t)NN * DH * 2);  // GEMM out (bf16)
    ushort* hB     = (ushort*)alloc((size_t)NN * DH * 2);  // agg out (bf16)
    float* as_     = (float*)alloc(NN * 4);
    float* ad_     = (float*)alloc(NN * 4);
    int*   row_ptr = (int*)  alloc((NN + 1) * 4);
    // zero-region 1: counts | cursor | bn_sums | bn_sumsq (one memset)
    int*   counts  = (int*)  alloc((2 * NN + 2 * DH) * 4);
    int*   cursor  = counts + NN;
    float* bn_sums = (float*)(cursor + NN);
    float* bn_sumsq= bn_sums + DH;
    int*   csr_src = (int*)  alloc((size_t)EE * 4);
    int*   bsum    = (int*)  alloc(SCAN_NB * 4);
    // zero-region 2: pool | cnt (one memset)
    float* pool    = (float*)alloc((NG * DH + NG) * 4);
    float* cnt     = pool + NG * DH;
    float* f       = (float*)alloc(NG * 2 * DH * 4);
    float* fnrm    = (float*)alloc(NG * 2 * DH * 4);
    ushort* Wp1    = (ushort*)alloc(16384 * 2);
    ushort* Wp2    = (ushort*)alloc(16384 * 2);
    float* bn_part = (float*)alloc((size_t)BNS_NB * 256 * 4);  // 512 KB
    (void)ws_size; (void)in_sizes; (void)n_in; (void)out_size;

    auto cdiv = [](int a, int b) { return (a + b - 1) / b; };

    hipMemsetAsync(counts, 0, (size_t)(2 * NN + 2 * DH) * 4, stream);
    hipMemsetAsync(pool, 0, (size_t)(NG * DH + NG) * 4, stream);

    // W pre-pack + histogram (merged); CSR build (shared by both layers)
    k_wpack_hist<<<2 + cdiv(NE, 256), 256, 0, stream>>>(W1, W2, Wp1, Wp2, ei, counts);
    k_scan1<<<SCAN_NB, 256, 0, stream>>>(counts, row_ptr, bsum);
    k_scan3<<<SCAN_NB, 256, 0, stream>>>(row_ptr, bsum);
    k_scatter<<<SC_RANGES * SC_CHUNKS, 256, 0, stream>>>(ei, row_ptr, cursor, csr_src);

    // GAT layer 1
    k_gemm_att<false><<<cdiv(NN, GR), 256, 0, stream>>>(x, Wp1, a_src1, a_dst1, hA, as_, ad_, NN);
    k_gat_agg<<<cdiv(NN, 4), 256, 0, stream>>>(hA, as_, ad_, row_ptr, csr_src, b1, hB);

    // GAT layer 2 (input hB is bf16)
    k_gemm_att<true><<<cdiv(NN, GR), 256, 0, stream>>>(hB, Wp2, a_src2, a_dst2, hA, as_, ad_, NN);
    k_gat_agg<<<cdiv(NN, 4), 256, 0, stream>>>(hA, as_, ad_, row_ptr, csr_src, b2, hB);

    // BN + relu + mean-pool (bn_fin folded into bn_pool)
    k_bn_stats<<<BNS_NB, 256, 0, stream>>>(hB, bn_part);
    k_bn_red<<<16, 256, 0, stream>>>(bn_part, bn_sums, bn_sumsq);
    k_bn_pool<<<cdiv(NN, 128), 256, 0, stream>>>(hB, bn_sums, bn_sumsq, bn2_g, bn2_b, batch, pool, cnt);

    // head
    k_head_docf<<<NG, 256, 0, stream>>>(docf, doc_W, doc_b, pool, cnt, f);
    k_head_bnf<<<1, 256, 0, stream>>>(f, bnf_g, bnf_b, fnrm);
    k_head_out<<<NG, 256, 0, stream>>>(fnrm, fus_W, fus_b, task_W, task_b, time_W, time_b, out);
}